// Round 11
// baseline (271.883 us; speedup 1.0000x reference)
//
#include <hip/hip_runtime.h>
#include <hip/hip_bf16.h>
#include <cstdint>
#include <cstddef>

// B=4, T=256, U=64, H=512, K=512, V=1024; M = 65536 rows, log_softmax over V.
// Round 11: SPLIT. Kernel A (joint_gemm): 256x256 tiles (BM=256 -> 4x less
// L2 B-traffic than BM=64; fused softmax constraint dropped), 16 waves
// (4Mx4N of 64x64), A-tile [256][32] bf16 double-buffered in LDS with
// in-loop tanh recompute, B direct L2->reg (4 waves share via L1).
// Stores fp16 logits into the first 2KB of each out-row's 4KB slot.
// Kernel B (lsm): streaming log-softmax, 1 wave/row, NO max pass
// (logits bounded by ||W2col||_1 ~ 20 << 88), reads fp16, writes f32.

typedef __attribute__((ext_vector_type(8))) short short8;
typedef __attribute__((ext_vector_type(4))) float f32x4;

#define BS_CHUNK 65536                // one BK=32 chunk of W2 image: 1024 cols * 64 B

// ws layout
#define WS_EP_OFF 0                           // 1024*512 f32 = 2 MiB
#define WS_DP_OFF (1024 * 512 * 4)            // 256*512 f32 = 512 KiB
#define WS_W2_OFF (WS_DP_OFF + 256 * 512 * 4) // W2 bf16 image: 16 chunks * 64 KiB

__device__ __forceinline__ unsigned short f2bf(float x) {
  unsigned int u = __builtin_bit_cast(unsigned int, x);
  u += 0x7FFFu + ((u >> 16) & 1u);
  return (unsigned short)(u >> 16);
}

__device__ __forceinline__ unsigned short f2h(float x) {
  _Float16 h = (_Float16)x;
  return __builtin_bit_cast(unsigned short, h);
}

__device__ __forceinline__ float h2f(unsigned short u) {
  return (float)__builtin_bit_cast(_Float16, u);
}

__device__ __forceinline__ float fast_tanh(float x) {
  float ax = fabsf(x);
  float e = __expf(-2.0f * ax);
  float t = (1.0f - e) * __builtin_amdgcn_rcpf(1.0f + e);
  return copysignf(t, x);
}

// ---------------------------------------------------------------------------
// prep (fused): blocks 0..159 -> ep/dp projections (8 rows each);
//               blocks 160..191 -> W2 repack to bf16 image:
//   w2st[kc*65536 + v*64 + ki*2] = bf16(W2[kc*32+ki][v])
// ---------------------------------------------------------------------------
__global__ __launch_bounds__(512) void prep(
    const float* __restrict__ enc, const float* __restrict__ dec,
    const float* __restrict__ W1, const float* __restrict__ b1,
    const float* __restrict__ W2,
    float* __restrict__ ep, float* __restrict__ dp, char* __restrict__ w2st) {
  __shared__ float As[8 * 512];
  const int tid = threadIdx.x;
  if (blockIdx.x < 160) {
    const int r0 = blockIdx.x * 8;
    const bool isenc = (r0 < 1024);
    const float* A = isenc ? (enc + (size_t)r0 * 512) : (dec + (size_t)(r0 - 1024) * 512);
    const float* W = isenc ? W1 : (W1 + 512 * 512);
    float* O = isenc ? (ep + (size_t)r0 * 512) : (dp + (size_t)(r0 - 1024) * 512);

    for (int idx = tid; idx < 8 * 512; idx += 512) As[idx] = A[idx];
    __syncthreads();

    const int c = tid;
    float acc[8];
#pragma unroll
    for (int r = 0; r < 8; ++r) acc[r] = 0.0f;
    const float4* As4 = (const float4*)As;
#pragma unroll 2
    for (int k4 = 0; k4 < 128; ++k4) {
      const int kb = k4 * 4;
      float w0 = W[(size_t)(kb + 0) * 512 + c];
      float w1 = W[(size_t)(kb + 1) * 512 + c];
      float w2 = W[(size_t)(kb + 2) * 512 + c];
      float w3 = W[(size_t)(kb + 3) * 512 + c];
#pragma unroll
      for (int r = 0; r < 8; ++r) {
        float4 a = As4[r * 128 + k4];
        acc[r] += a.x * w0 + a.y * w1 + a.z * w2 + a.w * w3;
      }
    }
    const float bias = isenc ? b1[c] : 0.0f;
#pragma unroll
    for (int r = 0; r < 8; ++r) O[(size_t)r * 512 + c] = acc[r] + bias;
  } else {
    const int g = (blockIdx.x - 160) * 512 + tid;  // 0..16383
    const int v = g & 1023;
    const int kc = g >> 10;
    unsigned short vals[32];
#pragma unroll
    for (int ki = 0; ki < 32; ++ki)
      vals[ki] = f2bf(W2[(size_t)(kc * 32 + ki) * 1024 + v]);
    uint4* dst = (uint4*)(w2st + (size_t)kc * BS_CHUNK + (size_t)v * 64);
    const uint4* s = (const uint4*)vals;
    dst[0] = s[0]; dst[1] = s[1]; dst[2] = s[2]; dst[3] = s[3];
  }
}

// ---------------------------------------------------------------------------
// joint_gemm: block = 256 rows x 256 cols; grid 1024 (m = bid&255, n = bid>>8).
// 1024 thr = 16 waves (4M x 4N), wave tile 64x64, acc 64 f32.
// A-tile [256][32] bf16 per chunk, double-buffered; tanh recomputed in-loop.
// B frags direct from L2 (16 KB/chunk/block; 4 waves share each frag via L1).
// Epilogue: +b2, fp16, store into out-row slot's first 2 KB (ushort lane).
// ---------------------------------------------------------------------------
__global__ __launch_bounds__(1024, 4) void joint_gemm(
    const float* __restrict__ ep, const float* __restrict__ dp,
    const char* __restrict__ w2st, const float* __restrict__ b2,
    float* __restrict__ out) {
  __shared__ char As[2][256 * 64];   // [parity][row*64 + swizzled 16B slot]

  const int tid = threadIdx.x;
  const int wave = tid >> 6, lane = tid & 63;
  const int lo = lane & 15, hi = lane >> 4;
  const int wm = wave >> 2, wn = wave & 3;
  const int m = blockIdx.x & 255, n = blockIdx.x >> 8;
  const int row0 = m * 256;
  const int nbase = n * 256 + wn * 64;

  // tanh mapping: thread -> row tr (0..255), 8-col slot ts (0..3)
  const int tr = tid >> 2;
  const int ts = tid & 3;
  const int grow = row0 + tr;
  const int gbt = grow >> 6;                       // b*256 + t
  const int gdr = ((gbt >> 8) << 6) + (grow & 63); // b*64 + u
  const float* eprow = ep + (size_t)gbt * 512 + ts * 8;
  const float* dprow = dp + (size_t)gdr * 512 + ts * 8;
  // swizzled write offset: slot ^= (row>>1)&3 -> conflict-free b128 r/w
  const int wofs = tr * 64 + ((ts ^ ((tr >> 1) & 3)) << 4);

  const char* bbase = w2st + (size_t)(nbase + lo) * 64 + hi * 16;

  // prologue: tanh chunk 0 -> As[0]
  {
    float e[8], d[8];
    *(float4*)(e) = *(const float4*)(eprow);
    *(float4*)(e + 4) = *(const float4*)(eprow + 4);
    *(float4*)(d) = *(const float4*)(dprow);
    *(float4*)(d + 4) = *(const float4*)(dprow + 4);
    unsigned short h[8];
#pragma unroll
    for (int j = 0; j < 8; ++j) h[j] = f2bf(fast_tanh(e[j] + d[j]));
    *(uint4*)(As[0] + wofs) = *(const uint4*)h;
  }

  f32x4 acc[4][4];
#pragma unroll
  for (int mi = 0; mi < 4; ++mi)
#pragma unroll
    for (int ni = 0; ni < 4; ++ni)
#pragma unroll
      for (int j = 0; j < 4; ++j) acc[mi][ni][j] = 0.0f;

  __syncthreads();

#pragma unroll 1
  for (int kc = 0; kc < 16; ++kc) {
    // B frags for chunk kc (issued first: latency hides under tanh VALU)
    short8 b[4];
    const char* bp = bbase + (size_t)kc * BS_CHUNK;
#pragma unroll
    for (int ni = 0; ni < 4; ++ni) b[ni] = *(const short8*)(bp + ni * 1024);

    // tanh for chunk kc+1 into the other buffer
    if (kc < 15) {
      float e[8], d[8];
      const float* e_ = eprow + (kc + 1) * 32;
      const float* d_ = dprow + (kc + 1) * 32;
      *(float4*)(e) = *(const float4*)(e_);
      *(float4*)(e + 4) = *(const float4*)(e_ + 4);
      *(float4*)(d) = *(const float4*)(d_);
      *(float4*)(d + 4) = *(const float4*)(d_ + 4);
      unsigned short h[8];
#pragma unroll
      for (int j = 0; j < 8; ++j) h[j] = f2bf(fast_tanh(e[j] + d[j]));
      *(uint4*)(As[(kc + 1) & 1] + wofs) = *(const uint4*)h;
    }

    // A frags from current buffer
    short8 a[4];
#pragma unroll
    for (int mi = 0; mi < 4; ++mi) {
      const int r = wm * 64 + mi * 16 + lo;
      a[mi] = *(const short8*)(As[kc & 1] + r * 64 + ((hi ^ ((r >> 1) & 3)) << 4));
    }
#pragma unroll
    for (int ni = 0; ni < 4; ++ni)
#pragma unroll
      for (int mi = 0; mi < 4; ++mi)
        acc[mi][ni] = __builtin_amdgcn_mfma_f32_16x16x32_bf16(a[mi], b[ni], acc[mi][ni], 0, 0, 0);

    __syncthreads();  // next-buffer writes visible; current-buffer reads done
  }

  // epilogue: +b2, fp16, store logits into out-row slots (first 2 KB each)
  float b2v[4];
#pragma unroll
  for (int ni = 0; ni < 4; ++ni) b2v[ni] = b2[nbase + ni * 16 + lo];

  unsigned short* outh = (unsigned short*)out;
#pragma unroll
  for (int mi = 0; mi < 4; ++mi)
#pragma unroll
    for (int r = 0; r < 4; ++r) {
      const int row = row0 + wm * 64 + mi * 16 + hi * 4 + r;
      unsigned short* op = outh + (size_t)row * 2048 + nbase + lo;
#pragma unroll
      for (int ni = 0; ni < 4; ++ni)
        op[ni * 16] = f2h(acc[mi][ni][r] + b2v[ni]);
    }
}

// ---------------------------------------------------------------------------
// lsm: streaming log-softmax. One wave per row (grid-stride, 8 rows/wave).
// Reads 1024 fp16 logits from the row's slot (first 2 KB), computes
// out = l - log(sum exp(l)) (no max: logits bounded ~20), writes 1024 f32.
// ---------------------------------------------------------------------------
__global__ __launch_bounds__(256) void lsm(float* __restrict__ out) {
  const int gw = (blockIdx.x * 256 + threadIdx.x) >> 6;  // global wave id 0..8191
  const int lane = threadIdx.x & 63;
#pragma unroll 1
  for (int r = gw; r < 65536; r += 8192) {
    const unsigned short* lp = (const unsigned short*)out + (size_t)r * 2048 + lane * 16;
    uint4 q0 = *(const uint4*)(lp);
    uint4 q1 = *(const uint4*)(lp + 8);
    unsigned short us[16];
    *(uint4*)(us) = q0;
    *(uint4*)(us + 8) = q1;
    float v[16];
#pragma unroll
    for (int j = 0; j < 16; ++j) v[j] = h2f(us[j]);
    float s = 0.0f;
#pragma unroll
    for (int j = 0; j < 16; ++j) s += __expf(v[j]);
#pragma unroll
    for (int off = 1; off < 64; off <<= 1) s += __shfl_xor(s, off);
    const float ls = __logf(s);
    float o[16];
#pragma unroll
    for (int j = 0; j < 16; ++j) o[j] = v[j] - ls;
    float* op = out + (size_t)r * 1024 + lane * 16;
    *(float4*)(op) = *(const float4*)(o);
    *(float4*)(op + 4) = *(const float4*)(o + 4);
    *(float4*)(op + 8) = *(const float4*)(o + 8);
    *(float4*)(op + 12) = *(const float4*)(o + 12);
  }
}

// ---------------------------------------------------------------------------
extern "C" void kernel_launch(void* const* d_in, const int* in_sizes, int n_in,
                              void* d_out, int out_size, void* d_ws, size_t ws_size,
                              hipStream_t stream) {
  const float* enc = (const float*)d_in[0];
  const float* dec = (const float*)d_in[1];
  const float* W1  = (const float*)d_in[2];
  const float* b1  = (const float*)d_in[3];
  const float* W2  = (const float*)d_in[4];
  const float* b2  = (const float*)d_in[5];
  float* out = (float*)d_out;

  char* ws = (char*)d_ws;
  float* ep = (float*)(ws + WS_EP_OFF);
  float* dp = (float*)(ws + WS_DP_OFF);
  char* w2st = ws + WS_W2_OFF;

  prep<<<192, 512, 0, stream>>>(enc, dec, W1, b1, W2, ep, dp, w2st);
  joint_gemm<<<1024, 1024, 0, stream>>>(ep, dp, w2st, b2, out);
  lsm<<<2048, 256, 0, stream>>>(out);
}

// Round 12
// 208.746 us; speedup vs baseline: 1.3025x; 1.3025x over previous
//
#include <hip/hip_runtime.h>
#include <hip/hip_bf16.h>
#include <cstdint>
#include <cstddef>

// B=4, T=256, U=64, H=512, K=512, V=1024; M = 65536 rows, log_softmax over V.
// Round 12: fused fp8 + T3/T4 pipeline. Block = 64 rows x V=1024, 1024 thr =
// 16 waves, wave tile 64x64 (acc 64 f32), mfma_f32_16x16x32_fp8_fp8.
// B (W2 fp8 image, 512 KB, L2-resident) staged per BK=32 chunk (32 KB) via
// global_load_lds into a DOUBLE buffer with counted s_waitcnt vmcnt(2)
// (never 0 mid-loop). A = tanh(ep+dp) in fp8 LDS [64][528] (pad: conflict-
// free ds_read_b64). B image pre-swizzled in prep so linear gload_lds +
// XOR'd ds_read is bank-conflict-free (m201 pattern). ep staged to LDS once.

typedef __attribute__((ext_vector_type(4))) float f32x4;

#define BS_CHUNK 32768                 // one BK=32 chunk: 1024 cols * 32 B (fp8)

// ws layout
#define WS_EP_OFF 0                            // 1024*512 f32 = 2 MiB
#define WS_DP_OFF (1024 * 512 * 4)             // 256*512 f32 = 512 KiB
#define WS_W2_OFF (WS_DP_OFF + 256 * 512 * 4)  // W2 fp8 image: 16 * 32 KiB

#define ASTRIDE 528                    // 512 + 16 pad: 16B-aligned rows, 2-way banks
#define LDS_EP 33792                   // A = 64*528 = 33792 B
#define LDS_B0 36864                   // ep row: 2 KB (+pad)
#define LDS_B1 69632
#define SMEM_TOTAL 102400              // 100 KiB; reductions alias B0 post-loop

__device__ __forceinline__ unsigned short f2bf(float x) {
  unsigned int u = __builtin_bit_cast(unsigned int, x);
  u += 0x7FFFu + ((u >> 16) & 1u);
  return (unsigned short)(u >> 16);
}

__device__ __forceinline__ float fast_tanh(float x) {
  float ax = fabsf(x);
  float e = __expf(-2.0f * ax);
  float t = (1.0f - e) * __builtin_amdgcn_rcpf(1.0f + e);
  return copysignf(t, x);
}

// ---- fp8 e4m3fn conversion (RTNE, saturating) ----
#if __has_builtin(__builtin_amdgcn_cvt_pk_fp8_f32)
__device__ __forceinline__ unsigned int f2fp8x4(float a, float b, float c, float d) {
  unsigned int w = 0;
  w = (unsigned int)__builtin_amdgcn_cvt_pk_fp8_f32(a, b, (int)w, false);
  w = (unsigned int)__builtin_amdgcn_cvt_pk_fp8_f32(c, d, (int)w, true);
  return w;
}
#else
__device__ __forceinline__ unsigned int enc_e4m3(float x) {
  unsigned int u = __builtin_bit_cast(unsigned int, x);
  unsigned int s = (u >> 24) & 0x80u;
  float ax = fabsf(x);
  if (!(ax < 448.0f)) return s | 0x7Eu;
  if (ax < 0.0009765625f) return s;
  int e; float fr = frexpf(ax, &e);       // ax = fr*2^e, fr in [0.5,1)
  int E = e + 6;
  if (E >= 1) {
    unsigned int m = (unsigned int)rintf(fr * 16.0f);  // [8,16]
    if (m == 16u) { m = 8u; E += 1; }
    if (E >= 16) return s | 0x7Eu;
    return s | ((unsigned int)E << 3) | (m - 8u);
  } else {
    unsigned int m = (unsigned int)rintf(ax * 512.0f);
    if (m >= 8u) return s | 0x08u;
    return s | m;
  }
}
__device__ __forceinline__ unsigned int f2fp8x4(float a, float b, float c, float d) {
  return enc_e4m3(a) | (enc_e4m3(b) << 8) | (enc_e4m3(c) << 16) | (enc_e4m3(d) << 24);
}
#endif

// ---------------------------------------------------------------------------
// prep: blocks 0..159 -> ep/dp projections (8 rows each);
//       blocks 160..191 -> W2 repack to fp8 image, PRE-SWIZZLED:
//   logical byte (v*32 + ki); qword g=ki>>3 stored at slot g ^ ((v>>2)&3).
// ---------------------------------------------------------------------------
__global__ __launch_bounds__(512) void prep(
    const float* __restrict__ enc, const float* __restrict__ dec,
    const float* __restrict__ W1, const float* __restrict__ b1,
    const float* __restrict__ W2,
    float* __restrict__ ep, float* __restrict__ dp, char* __restrict__ w8st) {
  __shared__ float As[8 * 512];
  const int tid = threadIdx.x;
  if (blockIdx.x < 160) {
    const int r0 = blockIdx.x * 8;
    const bool isenc = (r0 < 1024);
    const float* A = isenc ? (enc + (size_t)r0 * 512) : (dec + (size_t)(r0 - 1024) * 512);
    const float* W = isenc ? W1 : (W1 + 512 * 512);
    float* O = isenc ? (ep + (size_t)r0 * 512) : (dp + (size_t)(r0 - 1024) * 512);

    for (int idx = tid; idx < 8 * 512; idx += 512) As[idx] = A[idx];
    __syncthreads();

    const int c = tid;
    float acc[8];
#pragma unroll
    for (int r = 0; r < 8; ++r) acc[r] = 0.0f;
    const float4* As4 = (const float4*)As;
#pragma unroll 2
    for (int k4 = 0; k4 < 128; ++k4) {
      const int kb = k4 * 4;
      float w0 = W[(size_t)(kb + 0) * 512 + c];
      float w1 = W[(size_t)(kb + 1) * 512 + c];
      float w2 = W[(size_t)(kb + 2) * 512 + c];
      float w3 = W[(size_t)(kb + 3) * 512 + c];
#pragma unroll
      for (int r = 0; r < 8; ++r) {
        float4 a = As4[r * 128 + k4];
        acc[r] += a.x * w0 + a.y * w1 + a.z * w2 + a.w * w3;
      }
    }
    const float bias = isenc ? b1[c] : 0.0f;
#pragma unroll
    for (int r = 0; r < 8; ++r) O[(size_t)r * 512 + c] = acc[r] + bias;
  } else {
    const int g = (blockIdx.x - 160) * 512 + tid;  // 0..16383 = (kc, v)
    const int v = g & 1023;
    const int kc = g >> 10;
    const int s = (v >> 2) & 3;
    unsigned long long* dst =
        (unsigned long long*)(w8st + (size_t)kc * BS_CHUNK + (size_t)v * 32);
#pragma unroll
    for (int q = 0; q < 4; ++q) {
      float f[8];
#pragma unroll
      for (int j = 0; j < 8; ++j)
        f[j] = W2[(size_t)(kc * 32 + q * 8 + j) * 1024 + v];
      unsigned int lo = f2fp8x4(f[0], f[1], f[2], f[3]);
      unsigned int hi = f2fp8x4(f[4], f[5], f[6], f[7]);
      dst[q ^ s] = (unsigned long long)lo | ((unsigned long long)hi << 32);
    }
  }
}

// ---------------------------------------------------------------------------
// stage one 32-KB chunk: 16 waves x 2 KB, 2 gload_lds (1 KB each) per wave.
// LDS dest = linear (wave-uniform base + lane*16) -- required by HW.
// ---------------------------------------------------------------------------
__device__ __forceinline__ void stage32(const char* __restrict__ src, char* dst,
                                        int wave, int lane) {
  const int off = wave * 2048 + lane * 16;
#pragma unroll
  for (int j = 0; j < 2; ++j)
    __builtin_amdgcn_global_load_lds(
        (const __attribute__((address_space(1))) unsigned int*)(src + off + j * 1024),
        (__attribute__((address_space(3))) unsigned int*)(dst + off + j * 1024), 16, 0, 0);
}

// ---------------------------------------------------------------------------
// joint: block = 64 rows (one (b,t)) x V=1024; 16 waves; wave w owns all 64
// rows x cols [w*64, w*64+64): 4 m-frags x 4 n-frags, acc 64 f32. fp8 MFMA.
// ---------------------------------------------------------------------------
__global__ __launch_bounds__(1024, 4) void joint(
    const float* __restrict__ ep, const float* __restrict__ dp,
    const char* __restrict__ w8st, const float* __restrict__ b2,
    float* __restrict__ out) {
  extern __shared__ char smem[];
  char* Asm = smem;                         // [64][528] fp8 hidden tile
  float* epL = (float*)(smem + LDS_EP);     // [512] ep row
  char* Bs0 = smem + LDS_B0;                // 32 KB chunk buffers
  char* Bs1 = smem + LDS_B1;
  float* redM = (float*)(smem + LDS_B0);    // aliases B0 after K-loop
  float* redF = redM + 1024;
  float* redS = redF + 64;
  float* redF2 = redS + 1024;

  const int tid = threadIdx.x;
  const int wave = tid >> 6, lane = tid & 63;
  const int lo = lane & 15, hi = lane >> 4;
  const int bt = blockIdx.x;
  const int m0 = bt * 64;
  const int dprow0 = (bt >> 8) * 64;
  const int nbase = wave * 64;
  const int krot = bt & 15;

  float b2v[4];
#pragma unroll
  for (int ni = 0; ni < 4; ++ni) b2v[ni] = b2[nbase + ni * 16 + lo];

  // -- prologue: issue stages of chunks rot(0), rot(1) FIRST --
  stage32(w8st + (size_t)krot * BS_CHUNK, Bs0, wave, lane);
  stage32(w8st + (size_t)((krot + 1) & 15) * BS_CHUNK, Bs1, wave, lane);

  // ep row -> LDS (once)
  if (tid < 128) ((float4*)epL)[tid] = ((const float4*)(ep + (size_t)bt * 512))[tid];

  // dp loads for tanh: thread = (row = tid&63, cols c0..c0+31)
  const int arow = tid & 63;
  const int c0 = (tid >> 6) * 32;
  float d[32];
  {
    const float* dpr = dp + (size_t)(dprow0 + arow) * 512 + c0;
#pragma unroll
    for (int j = 0; j < 8; ++j) *(float4*)(d + j * 4) = ((const float4*)dpr)[j];
  }
  __syncthreads();  // epL visible (also drains prologue loads once -- fine)

  // -- tanh: h = tanh(ep + dp) -> fp8 -> A LDS --
  {
    unsigned int w8[8];
#pragma unroll
    for (int q = 0; q < 8; ++q) {
      float h0 = fast_tanh(epL[c0 + q * 4 + 0] + d[q * 4 + 0]);
      float h1 = fast_tanh(epL[c0 + q * 4 + 1] + d[q * 4 + 1]);
      float h2 = fast_tanh(epL[c0 + q * 4 + 2] + d[q * 4 + 2]);
      float h3 = fast_tanh(epL[c0 + q * 4 + 3] + d[q * 4 + 3]);
      w8[q] = f2fp8x4(h0, h1, h2, h3);
    }
    uint4* aw = (uint4*)(Asm + arow * ASTRIDE + c0);
    aw[0] = *(const uint4*)(w8);
    aw[1] = *(const uint4*)(w8 + 4);
  }

  f32x4 acc[4][4];
#pragma unroll
  for (int mi = 0; mi < 4; ++mi)
#pragma unroll
    for (int ni = 0; ni < 4; ++ni)
#pragma unroll
      for (int j = 0; j < 4; ++j) acc[mi][ni][j] = 0.0f;

  asm volatile("s_waitcnt lgkmcnt(0)" ::: "memory");
  __builtin_amdgcn_s_barrier();             // A visible to all waves
  __builtin_amdgcn_sched_barrier(0);

  // per-lane swizzled B offset within a chunk (pre-swizzled image, m201)
  const int bswz = (hi * 8) ^ (((lo >> 2) & 3) << 3);

  // -- K loop: 16 chunks, double-buffered, counted vmcnt --
#define K_ITER(I, RD)                                                            \
  {                                                                              \
    const int i_ = (I);                                                          \
    if (i_ >= 14) asm volatile("s_waitcnt vmcnt(0)" ::: "memory");               \
    else          asm volatile("s_waitcnt vmcnt(2)" ::: "memory");               \
    __builtin_amdgcn_s_barrier();   /* chunk i resident for everyone */          \
    __builtin_amdgcn_sched_barrier(0);                                           \
    const int gc = (i_ + krot) & 15;                                             \
    unsigned long long a[4], b[4];                                               \
    _Pragma("unroll")                                                            \
    for (int ni = 0; ni < 4; ++ni)                                               \
      b[ni] = *(const unsigned long long*)(RD + (size_t)(nbase + ni * 16 + lo) * 32 + bswz); \
    _Pragma("unroll")                                                            \
    for (int mi = 0; mi < 4; ++mi)                                               \
      a[mi] = *(const unsigned long long*)(Asm + (size_t)(mi * 16 + lo) * ASTRIDE + gc * 32 + hi * 8); \
    asm volatile("s_waitcnt lgkmcnt(0)" ::: "memory");                           \
    __builtin_amdgcn_sched_barrier(0);                                           \
    __builtin_amdgcn_s_barrier();   /* all waves done reading RD */              \
    __builtin_amdgcn_sched_barrier(0);                                           \
    if (i_ < 14)                                                                 \
      stage32(w8st + (size_t)(((i_ + 2 + krot) & 15)) * BS_CHUNK, RD, wave, lane); \
    __builtin_amdgcn_s_setprio(1);                                               \
    _Pragma("unroll")                                                            \
    for (int ni = 0; ni < 4; ++ni)                                               \
      _Pragma("unroll")                                                          \
      for (int mi = 0; mi < 4; ++mi)                                             \
        acc[mi][ni] = __builtin_amdgcn_mfma_f32_16x16x32_fp8_fp8(                \
            (long)a[mi], (long)b[ni], acc[mi][ni], 0, 0, 0);                     \
    __builtin_amdgcn_s_setprio(0);                                               \
  }

#pragma unroll 1
  for (int i2 = 0; i2 < 8; ++i2) {
    K_ITER(i2 * 2, Bs0);
    K_ITER(i2 * 2 + 1, Bs1);
  }
#undef K_ITER

  // -- epilogue: +b2, log_softmax over V, store (reds alias B0) --
#pragma unroll
  for (int mi = 0; mi < 4; ++mi)
#pragma unroll
    for (int ni = 0; ni < 4; ++ni)
#pragma unroll
      for (int j = 0; j < 4; ++j) acc[mi][ni][j] += b2v[ni];

  float pm[4][4];
#pragma unroll
  for (int mi = 0; mi < 4; ++mi)
#pragma unroll
    for (int r = 0; r < 4; ++r)
      pm[mi][r] = fmaxf(fmaxf(acc[mi][0][r], acc[mi][1][r]),
                        fmaxf(acc[mi][2][r], acc[mi][3][r]));
#pragma unroll
  for (int off = 1; off < 16; off <<= 1)
#pragma unroll
    for (int mi = 0; mi < 4; ++mi)
#pragma unroll
      for (int r = 0; r < 4; ++r)
        pm[mi][r] = fmaxf(pm[mi][r], __shfl_xor(pm[mi][r], off));
  if (lo == 0) {
#pragma unroll
    for (int mi = 0; mi < 4; ++mi)
#pragma unroll
      for (int r = 0; r < 4; ++r)
        redM[wave * 64 + mi * 16 + hi * 4 + r] = pm[mi][r];
  }
  asm volatile("s_waitcnt lgkmcnt(0)" ::: "memory");
  __builtin_amdgcn_s_barrier();
  {
    const int rr = tid >> 4, w = tid & 15;
    float v = redM[w * 64 + rr];
#pragma unroll
    for (int off = 1; off < 16; off <<= 1) v = fmaxf(v, __shfl_xor(v, off));
    if (w == 0) redF[rr] = v;
  }
  asm volatile("s_waitcnt lgkmcnt(0)" ::: "memory");
  __builtin_amdgcn_s_barrier();
  float rm[4][4];
#pragma unroll
  for (int mi = 0; mi < 4; ++mi)
#pragma unroll
    for (int r = 0; r < 4; ++r) rm[mi][r] = redF[mi * 16 + hi * 4 + r];

  float ps[4][4];
#pragma unroll
  for (int mi = 0; mi < 4; ++mi)
#pragma unroll
    for (int r = 0; r < 4; ++r) {
      float s = 0.0f;
#pragma unroll
      for (int ni = 0; ni < 4; ++ni) s += __expf(acc[mi][ni][r] - rm[mi][r]);
      ps[mi][r] = s;
    }
#pragma unroll
  for (int off = 1; off < 16; off <<= 1)
#pragma unroll
    for (int mi = 0; mi < 4; ++mi)
#pragma unroll
      for (int r = 0; r < 4; ++r)
        ps[mi][r] += __shfl_xor(ps[mi][r], off);
  if (lo == 0) {
#pragma unroll
    for (int mi = 0; mi < 4; ++mi)
#pragma unroll
      for (int r = 0; r < 4; ++r)
        redS[wave * 64 + mi * 16 + hi * 4 + r] = ps[mi][r];
  }
  asm volatile("s_waitcnt lgkmcnt(0)" ::: "memory");
  __builtin_amdgcn_s_barrier();
  {
    const int rr = tid >> 4, w = tid & 15;
    float v = redS[w * 64 + rr];
#pragma unroll
    for (int off = 1; off < 16; off <<= 1) v += __shfl_xor(v, off);
    if (w == 0) redF2[rr] = v;
  }
  asm volatile("s_waitcnt lgkmcnt(0)" ::: "memory");
  __builtin_amdgcn_s_barrier();

#pragma unroll
  for (int mi = 0; mi < 4; ++mi)
#pragma unroll
    for (int r = 0; r < 4; ++r) {
      const int row = mi * 16 + hi * 4 + r;
      const float sub = rm[mi][r] + __logf(redF2[row]);
      float* op = out + (size_t)(m0 + row) * 1024 + nbase + lo;
#pragma unroll
      for (int ni = 0; ni < 4; ++ni) op[ni * 16] = acc[mi][ni][r] - sub;
    }
}

// ---------------------------------------------------------------------------
extern "C" void kernel_launch(void* const* d_in, const int* in_sizes, int n_in,
                              void* d_out, int out_size, void* d_ws, size_t ws_size,
                              hipStream_t stream) {
  const float* enc = (const float*)d_in[0];
  const float* dec = (const float*)d_in[1];
  const float* W1  = (const float*)d_in[2];
  const float* b1  = (const float*)d_in[3];
  const float* W2  = (const float*)d_in[4];
  const float* b2  = (const float*)d_in[5];
  float* out = (float*)d_out;

  char* ws = (char*)d_ws;
  float* ep = (float*)(ws + WS_EP_OFF);
  float* dp = (float*)(ws + WS_DP_OFF);
  char* w8st = ws + WS_W2_OFF;

  prep<<<192, 512, 0, stream>>>(enc, dec, W1, b1, W2, ep, dp, w8st);
  joint<<<1024, 1024, SMEM_TOTAL, stream>>>(ep, dp, w8st, b2, out);
}

// Round 13
// 193.345 us; speedup vs baseline: 1.4062x; 1.0797x over previous
//
#include <hip/hip_runtime.h>
#include <hip/hip_bf16.h>
#include <cstdint>
#include <cstddef>

// B=4, T=256, U=64, H=512, K=512, V=1024; M = 65536 rows, log_softmax over V.
// Round 13: BARRIER-FREE K-loop with per-wave-PRIVATE B staging.
// Block = 64 rows x V=1024, 16 waves; wave w owns all 64 rows x cols
// [w*64,w*64+64) -> its B slice (2 KB/chunk) is PRIVATE. Stage it via
// global_load_lds into 3 private LDS buffers; per-wave counted
// s_waitcnt vmcnt(4); ZERO barriers between K iterations (vmcnt is per-wave,
// no cross-wave B sharing). fp8 e4m3 A and B (absmax 0.125 validated R12).
// LDS: A [64][528] fp8 (34 KB) + 16 waves x 3 x 2 KB (96 KB) = 130 KB.

typedef __attribute__((ext_vector_type(4))) float f32x4;

#define BS_CHUNK 32768                 // one BK=32 chunk: 1024 cols * 32 B (fp8)

// ws layout
#define WS_EP_OFF 0                            // 1024*512 f32 = 2 MiB
#define WS_DP_OFF (1024 * 512 * 4)             // 256*512 f32 = 512 KiB
#define WS_W2_OFF (WS_DP_OFF + 256 * 512 * 4)  // W2 fp8 image: 16 * 32 KiB

#define ASTRIDE 528                    // 512 + 16 pad
#define LDS_B 34816                    // A region padded to 34 KB
#define SMEM_TOTAL (34816 + 16 * 6144) // 133120 B = 130 KiB

__device__ __forceinline__ unsigned short f2bf(float x) {
  unsigned int u = __builtin_bit_cast(unsigned int, x);
  u += 0x7FFFu + ((u >> 16) & 1u);
  return (unsigned short)(u >> 16);
}

__device__ __forceinline__ float fast_tanh(float x) {
  float ax = fabsf(x);
  float e = __expf(-2.0f * ax);
  float t = (1.0f - e) * __builtin_amdgcn_rcpf(1.0f + e);
  return copysignf(t, x);
}

// ---- fp8 e4m3fn conversion (RTNE, saturating) ----
#if __has_builtin(__builtin_amdgcn_cvt_pk_fp8_f32)
__device__ __forceinline__ unsigned int f2fp8x4(float a, float b, float c, float d) {
  unsigned int w = 0;
  w = (unsigned int)__builtin_amdgcn_cvt_pk_fp8_f32(a, b, (int)w, false);
  w = (unsigned int)__builtin_amdgcn_cvt_pk_fp8_f32(c, d, (int)w, true);
  return w;
}
#else
__device__ __forceinline__ unsigned int enc_e4m3(float x) {
  unsigned int u = __builtin_bit_cast(unsigned int, x);
  unsigned int s = (u >> 24) & 0x80u;
  float ax = fabsf(x);
  if (!(ax < 448.0f)) return s | 0x7Eu;
  if (ax < 0.0009765625f) return s;
  int e; float fr = frexpf(ax, &e);
  int E = e + 6;
  if (E >= 1) {
    unsigned int m = (unsigned int)rintf(fr * 16.0f);
    if (m == 16u) { m = 8u; E += 1; }
    if (E >= 16) return s | 0x7Eu;
    return s | ((unsigned int)E << 3) | (m - 8u);
  } else {
    unsigned int m = (unsigned int)rintf(ax * 512.0f);
    if (m >= 8u) return s | 0x08u;
    return s | m;
  }
}
__device__ __forceinline__ unsigned int f2fp8x4(float a, float b, float c, float d) {
  return enc_e4m3(a) | (enc_e4m3(b) << 8) | (enc_e4m3(c) << 16) | (enc_e4m3(d) << 24);
}
#endif

// ---------------------------------------------------------------------------
// prep: blocks 0..159 -> ep/dp projections (8 rows each);
//       blocks 160..191 -> W2 repack to LINEAR fp8 image:
//   w8st[kc*32768 + v*32 + ki] = fp8(W2[kc*32+ki][v])
// ---------------------------------------------------------------------------
__global__ __launch_bounds__(512) void prep(
    const float* __restrict__ enc, const float* __restrict__ dec,
    const float* __restrict__ W1, const float* __restrict__ b1,
    const float* __restrict__ W2,
    float* __restrict__ ep, float* __restrict__ dp, char* __restrict__ w8st) {
  __shared__ float As[8 * 512];
  const int tid = threadIdx.x;
  if (blockIdx.x < 160) {
    const int r0 = blockIdx.x * 8;
    const bool isenc = (r0 < 1024);
    const float* A = isenc ? (enc + (size_t)r0 * 512) : (dec + (size_t)(r0 - 1024) * 512);
    const float* W = isenc ? W1 : (W1 + 512 * 512);
    float* O = isenc ? (ep + (size_t)r0 * 512) : (dp + (size_t)(r0 - 1024) * 512);

    for (int idx = tid; idx < 8 * 512; idx += 512) As[idx] = A[idx];
    __syncthreads();

    const int c = tid;
    float acc[8];
#pragma unroll
    for (int r = 0; r < 8; ++r) acc[r] = 0.0f;
    const float4* As4 = (const float4*)As;
#pragma unroll 2
    for (int k4 = 0; k4 < 128; ++k4) {
      const int kb = k4 * 4;
      float w0 = W[(size_t)(kb + 0) * 512 + c];
      float w1 = W[(size_t)(kb + 1) * 512 + c];
      float w2 = W[(size_t)(kb + 2) * 512 + c];
      float w3 = W[(size_t)(kb + 3) * 512 + c];
#pragma unroll
      for (int r = 0; r < 8; ++r) {
        float4 a = As4[r * 128 + k4];
        acc[r] += a.x * w0 + a.y * w1 + a.z * w2 + a.w * w3;
      }
    }
    const float bias = isenc ? b1[c] : 0.0f;
#pragma unroll
    for (int r = 0; r < 8; ++r) O[(size_t)r * 512 + c] = acc[r] + bias;
  } else {
    const int g = (blockIdx.x - 160) * 512 + tid;  // 0..16383 = (kc, v)
    const int v = g & 1023;
    const int kc = g >> 10;
    unsigned long long* dst =
        (unsigned long long*)(w8st + (size_t)kc * BS_CHUNK + (size_t)v * 32);
#pragma unroll
    for (int q = 0; q < 4; ++q) {
      float f[8];
#pragma unroll
      for (int j = 0; j < 8; ++j)
        f[j] = W2[(size_t)(kc * 32 + q * 8 + j) * 1024 + v];
      unsigned int lo = f2fp8x4(f[0], f[1], f[2], f[3]);
      unsigned int hi = f2fp8x4(f[4], f[5], f[6], f[7]);
      dst[q] = (unsigned long long)lo | ((unsigned long long)hi << 32);
    }
  }
}

// ---------------------------------------------------------------------------
// stage a wave's private 2-KB slice (cols nbase..nbase+63) of chunk gc.
// 2 x global_load_lds(16B): lane l -> local col l>>1, half l&1 -> linear LDS.
// ---------------------------------------------------------------------------
__device__ __forceinline__ void stageW(const char* __restrict__ w8st, char* dst,
                                       int gc, int nbase, int lane) {
  const char* src = w8st + (size_t)gc * BS_CHUNK + (size_t)nbase * 32 + lane * 16;
#pragma unroll
  for (int j = 0; j < 2; ++j)
    __builtin_amdgcn_global_load_lds(
        (const __attribute__((address_space(1))) unsigned int*)(src + j * 1024),
        (__attribute__((address_space(3))) unsigned int*)(dst + j * 1024 + lane * 16),
        16, 0, 0);
}

// ---------------------------------------------------------------------------
// joint: block = 64 rows (one (b,t)) x V=1024; 16 waves; wave w owns all 64
// rows x cols [w*64, w*64+64): 4 m-frags x 4 n-frags, acc 64 f32. fp8 MFMA.
// ---------------------------------------------------------------------------
__global__ __launch_bounds__(1024, 4) void joint(
    const float* __restrict__ ep, const float* __restrict__ dp,
    const char* __restrict__ w8st, const float* __restrict__ b2,
    float* __restrict__ out) {
  extern __shared__ char smem[];
  char* Asm = smem;                          // [64][528] fp8 hidden tile
  float* redM = (float*)smem;                // aliases A after the K-loop
  float* redF = redM + 1024;
  float* redS = redF + 64;
  float* redF2 = redS + 1024;

  const int tid = threadIdx.x;
  const int wave = tid >> 6, lane = tid & 63;
  const int lo = lane & 15, hi = lane >> 4;
  const int bt = blockIdx.x;
  const int m0 = bt * 64;
  const int dprow0 = (bt >> 8) * 64;
  const int nbase = wave * 64;
  const int krot = bt & 15;
  char* Bw = smem + LDS_B + wave * 6144;     // 3 private 2-KB buffers

  // -- tanh global loads FIRST (their wait must not drain the stages) --
  const int arow = tid & 63;
  const int c0 = (tid >> 6) * 32;
  float ev[32], d[32];
  {
    const float* epr = ep + (size_t)bt * 512 + c0;
    const float* dpr = dp + (size_t)(dprow0 + arow) * 512 + c0;
#pragma unroll
    for (int j = 0; j < 8; ++j) *(float4*)(ev + j * 4) = ((const float4*)epr)[j];
#pragma unroll
    for (int j = 0; j < 8; ++j) *(float4*)(d + j * 4) = ((const float4*)dpr)[j];
  }
  __builtin_amdgcn_sched_barrier(0);   // keep ep/dp loads BEFORE the stages

  // -- issue stages of chunks rot(0..2) into private buffers 0..2 --
  stageW(w8st, Bw,        (krot) & 15,     nbase, lane);
  stageW(w8st, Bw + 2048, (krot + 1) & 15, nbase, lane);
  stageW(w8st, Bw + 4096, (krot + 2) & 15, nbase, lane);
  __builtin_amdgcn_sched_barrier(0);

  // -- tanh: h = tanh(ep+dp) -> fp8 -> A LDS (waits ep/dp, leaves 6 stages) --
  {
    unsigned int w8[8];
#pragma unroll
    for (int q = 0; q < 8; ++q) {
      float h0 = fast_tanh(ev[q * 4 + 0] + d[q * 4 + 0]);
      float h1 = fast_tanh(ev[q * 4 + 1] + d[q * 4 + 1]);
      float h2 = fast_tanh(ev[q * 4 + 2] + d[q * 4 + 2]);
      float h3 = fast_tanh(ev[q * 4 + 3] + d[q * 4 + 3]);
      w8[q] = f2fp8x4(h0, h1, h2, h3);
    }
    uint4* aw = (uint4*)(Asm + arow * ASTRIDE + c0);
    aw[0] = *(const uint4*)(w8);
    aw[1] = *(const uint4*)(w8 + 4);
  }

  f32x4 acc[4][4];
#pragma unroll
  for (int mi = 0; mi < 4; ++mi)
#pragma unroll
    for (int ni = 0; ni < 4; ++ni)
#pragma unroll
      for (int j = 0; j < 4; ++j) acc[mi][ni][j] = 0.0f;

  // A visible to all waves -- raw barrier, NO vmcnt drain (stages in flight)
  asm volatile("s_waitcnt lgkmcnt(0)" ::: "memory");
  __builtin_amdgcn_s_barrier();
  __builtin_amdgcn_sched_barrier(0);

  // -- K loop: 16 chunks, per-wave 3-deep pipeline, ZERO barriers --
#define K_IT(I, D)                                                               \
  {                                                                              \
    if ((I) <= 13)      asm volatile("s_waitcnt vmcnt(4)" ::: "memory");         \
    else if ((I) == 14) asm volatile("s_waitcnt vmcnt(2)" ::: "memory");         \
    else                asm volatile("s_waitcnt vmcnt(0)" ::: "memory");         \
    const int gc_ = ((I) + krot) & 15;                                           \
    unsigned long long a_[4], b_[4];                                             \
    const char* bp_ = Bw + (D) * 2048;                                           \
    _Pragma("unroll")                                                            \
    for (int ni = 0; ni < 4; ++ni)                                               \
      b_[ni] = *(const unsigned long long*)(bp_ + (ni * 16 + lo) * 32 + hi * 8); \
    _Pragma("unroll")                                                            \
    for (int mi = 0; mi < 4; ++mi)                                               \
      a_[mi] = *(const unsigned long long*)(Asm + (mi * 16 + lo) * ASTRIDE + gc_ * 32 + hi * 8); \
    asm volatile("s_waitcnt lgkmcnt(0)" ::: "memory");                           \
    __builtin_amdgcn_sched_barrier(0);                                           \
    if ((I) < 13) stageW(w8st, Bw + (D) * 2048, ((I) + 3 + krot) & 15, nbase, lane); \
    _Pragma("unroll")                                                            \
    for (int ni = 0; ni < 4; ++ni)                                               \
      _Pragma("unroll")                                                          \
      for (int mi = 0; mi < 4; ++mi)                                             \
        acc[mi][ni] = __builtin_amdgcn_mfma_f32_16x16x32_fp8_fp8(                \
            (long)a_[mi], (long)b_[ni], acc[mi][ni], 0, 0, 0);                   \
  }

  K_IT(0, 0)  K_IT(1, 1)  K_IT(2, 2)  K_IT(3, 0)
  K_IT(4, 1)  K_IT(5, 2)  K_IT(6, 0)  K_IT(7, 1)
  K_IT(8, 2)  K_IT(9, 0)  K_IT(10, 1) K_IT(11, 2)
  K_IT(12, 0) K_IT(13, 1) K_IT(14, 2) K_IT(15, 0)
#undef K_IT

  // -- epilogue: +b2, log_softmax over V, store (reds alias A region) --
  float b2v[4];
#pragma unroll
  for (int ni = 0; ni < 4; ++ni) b2v[ni] = b2[nbase + ni * 16 + lo];
#pragma unroll
  for (int mi = 0; mi < 4; ++mi)
#pragma unroll
    for (int ni = 0; ni < 4; ++ni)
#pragma unroll
      for (int j = 0; j < 4; ++j) acc[mi][ni][j] += b2v[ni];

  __syncthreads();  // all waves past their A reads; safe to alias reductions

  float pm[4][4];
#pragma unroll
  for (int mi = 0; mi < 4; ++mi)
#pragma unroll
    for (int r = 0; r < 4; ++r)
      pm[mi][r] = fmaxf(fmaxf(acc[mi][0][r], acc[mi][1][r]),
                        fmaxf(acc[mi][2][r], acc[mi][3][r]));
#pragma unroll
  for (int off = 1; off < 16; off <<= 1)
#pragma unroll
    for (int mi = 0; mi < 4; ++mi)
#pragma unroll
      for (int r = 0; r < 4; ++r)
        pm[mi][r] = fmaxf(pm[mi][r], __shfl_xor(pm[mi][r], off));
  if (lo == 0) {
#pragma unroll
    for (int mi = 0; mi < 4; ++mi)
#pragma unroll
      for (int r = 0; r < 4; ++r)
        redM[wave * 64 + mi * 16 + hi * 4 + r] = pm[mi][r];
  }
  __syncthreads();
  {
    const int rr = tid >> 4, w = tid & 15;
    float v = redM[w * 64 + rr];
#pragma unroll
    for (int off = 1; off < 16; off <<= 1) v = fmaxf(v, __shfl_xor(v, off));
    if (w == 0) redF[rr] = v;
  }
  __syncthreads();
  float rm[4][4];
#pragma unroll
  for (int mi = 0; mi < 4; ++mi)
#pragma unroll
    for (int r = 0; r < 4; ++r) rm[mi][r] = redF[mi * 16 + hi * 4 + r];

  float ps[4][4];
#pragma unroll
  for (int mi = 0; mi < 4; ++mi)
#pragma unroll
    for (int r = 0; r < 4; ++r) {
      float s = 0.0f;
#pragma unroll
      for (int ni = 0; ni < 4; ++ni) s += __expf(acc[mi][ni][r] - rm[mi][r]);
      ps[mi][r] = s;
    }
#pragma unroll
  for (int off = 1; off < 16; off <<= 1)
#pragma unroll
    for (int mi = 0; mi < 4; ++mi)
#pragma unroll
      for (int r = 0; r < 4; ++r)
        ps[mi][r] += __shfl_xor(ps[mi][r], off);
  if (lo == 0) {
#pragma unroll
    for (int mi = 0; mi < 4; ++mi)
#pragma unroll
      for (int r = 0; r < 4; ++r)
        redS[wave * 64 + mi * 16 + hi * 4 + r] = ps[mi][r];
  }
  __syncthreads();
  {
    const int rr = tid >> 4, w = tid & 15;
    float v = redS[w * 64 + rr];
#pragma unroll
    for (int off = 1; off < 16; off <<= 1) v += __shfl_xor(v, off);
    if (w == 0) redF2[rr] = v;
  }
  __syncthreads();

#pragma unroll
  for (int mi = 0; mi < 4; ++mi)
#pragma unroll
    for (int r = 0; r < 4; ++r) {
      const int row = mi * 16 + hi * 4 + r;
      const float sub = rm[mi][r] + __logf(redF2[row]);
      float* op = out + (size_t)(m0 + row) * 1024 + nbase + lo;
#pragma unroll
      for (int ni = 0; ni < 4; ++ni) op[ni * 16] = acc[mi][ni][r] - sub;
    }
}

// ---------------------------------------------------------------------------
extern "C" void kernel_launch(void* const* d_in, const int* in_sizes, int n_in,
                              void* d_out, int out_size, void* d_ws, size_t ws_size,
                              hipStream_t stream) {
  const float* enc = (const float*)d_in[0];
  const float* dec = (const float*)d_in[1];
  const float* W1  = (const float*)d_in[2];
  const float* b1  = (const float*)d_in[3];
  const float* W2  = (const float*)d_in[4];
  const float* b2  = (const float*)d_in[5];
  float* out = (float*)d_out;

  char* ws = (char*)d_ws;
  float* ep = (float*)(ws + WS_EP_OFF);
  float* dp = (float*)(ws + WS_DP_OFF);
  char* w8st = ws + WS_W2_OFF;

  prep<<<192, 512, 0, stream>>>(enc, dec, W1, b1, W2, ep, dp, w8st);
  joint<<<1024, 1024, SMEM_TOTAL, stream>>>(ep, dp, w8st, b2, out);
}